// Round 1
// 153.859 us; speedup vs baseline: 1.1054x; 1.1054x over previous
//
#include <hip/hip_runtime.h>
#include <hip/hip_fp16.h>

// SGConvolution: out = A @ (A @ x), A sparse COO (edge_row sorted).
// N=100000, E=1600000, D=64 (== wave width; lane d owns feature d).
//
// R4 -> R5:
//  - spmm1 accumulates DIRECTLY into fp16 via global_atomic_pk_add_f16
//    (unsafeAtomicAdd on __half2). Rows are sorted -> ~1-2 atomic flushes per
//    row, so fp16 atomic rounding (~2^-11 rel) is negligible vs 0.125 absmax.
//    This deletes the fp32 intermediate (25.6 MB zero + 25.6 MB atomic write
//    + 25.6 MB re-read + 12.8 MB cast write).
//  - All bookkeeping (cast x->fp16, zero h16b, zero out) fused into ONE prep
//    kernel: 6 dispatches/call -> 3.
//  - Gather pipeline (CH=16 double-buffered, readlane->SGPR addressing,
//    scalar row-boundary branch) carried over unchanged from R4.

#define N_NODES 100000
#define N_EDGES 1600000
#define D_FEAT  64
#define EPW     64    // edges per wave; 1600000 / 64 = 25000 waves exactly
#define CH      16    // gather chunk (pipeline stage) size

#define N_ELEM   (N_NODES * D_FEAT)          // 6,400,000 features
#define N_CAST   (N_ELEM / 4)                // 1,600,000 float4 cast tasks
#define N_Z16    (N_ELEM / 8)                // 800,000   16B zero tasks (h16b, 12.8 MB)
#define N_ZOUT   (N_ELEM / 4)                // 1,600,000 16B zero tasks (out, 25.6 MB)
#define PREP_TASKS (N_CAST + N_Z16 + N_ZOUT) // 4,000,000 -> 15625 blocks of 256

__device__ __forceinline__ float readlane_f(float x, int j) {
    return __uint_as_float(__builtin_amdgcn_readlane(__float_as_uint(x), j));
}

// Flush one wave-segment accumulator (64 lanes, lane d = feature d) to the
// output row. HALF_OUT: pack lane pairs into __half2 and use the native
// packed-fp16 atomic (global_atomic_pk_add_f16); else plain fp32 atomicAdd.
template <bool HALF_OUT>
__device__ __forceinline__ void flush(void* outp, int row, int lane, float acc) {
    if constexpr (HALF_OUT) {
        const float partner = __shfl_xor(acc, 1);      // wave-uniform call site
        if ((lane & 1) == 0) {
            __half2* o = (__half2*)outp;
            unsafeAtomicAdd(&o[(size_t)row * (D_FEAT / 2) + (lane >> 1)],
                            __floats2half2_rn(acc, partner));
        }
    } else {
        atomicAdd(&((float*)outp)[(size_t)row * D_FEAT + lane], acc);
    }
}

template <bool HALF_OUT>
__global__ __launch_bounds__(256) void sg_spmm(
    const __half* __restrict__ h,          // [N, 64] fp16 feature table
    const int*    __restrict__ erow,       // [E] sorted destination rows
    const int*    __restrict__ ecol,       // [E] source cols
    const float*  __restrict__ eval,       // [E] edge weights
    void*         __restrict__ outp)       // [N, 64] pre-zeroed fp16 or fp32
{
    const int lane  = threadIdx.x & 63;
    const int wave  = (int)((blockIdx.x * blockDim.x + threadIdx.x) >> 6);
    const int start = wave * EPW;          // grid sized exactly; no tail

    // Coalesced preload of this wave's 64 edge triples (lane i = edge start+i).
    const int   r_v = erow[start + lane];
    const int   c_v = ecol[start + lane];
    const float w_v = eval[start + lane];

    __half gbuf[2][CH];

    // prefetch chunk 0
#pragma unroll
    for (int j = 0; j < CH; ++j) {
        const int c = __builtin_amdgcn_readlane(c_v, j);          // SGPR col
        gbuf[0][j] = h[(size_t)c * D_FEAT + lane];
    }

    int   cur_row = __builtin_amdgcn_readlane(r_v, 0);
    float acc     = 0.0f;

#pragma unroll
    for (int k = 0; k < EPW / CH; ++k) {
        if (k + 1 < EPW / CH) {
            // prefetch chunk k+1 while folding chunk k
#pragma unroll
            for (int j = 0; j < CH; ++j) {
                const int c = __builtin_amdgcn_readlane(c_v, (k + 1) * CH + j);
                gbuf[(k + 1) & 1][j] = h[(size_t)c * D_FEAT + lane];
            }
        }
#pragma unroll
        for (int j = 0; j < CH; ++j) {
            const int e = k * CH + j;
            const int r = __builtin_amdgcn_readlane(r_v, e);      // SGPR row
            if (r != cur_row) {                                   // scalar branch
                flush<HALF_OUT>(outp, cur_row, lane, acc);
                acc = 0.0f;
                cur_row = r;
            }
            acc += readlane_f(w_v, e) * __half2float(gbuf[k & 1][j]);
        }
    }
    flush<HALF_OUT>(outp, cur_row, lane, acc);
}

// Fused bookkeeping: cast x -> h16a (fp16), zero h16b (spmm1 atomic target),
// zero out (spmm2 atomic target). One dispatch replaces 2 memsets + 2 casts.
__global__ __launch_bounds__(256) void prep(
    const float* __restrict__ x,
    __half*      __restrict__ h16a,
    __half*      __restrict__ h16b,
    float*       __restrict__ out)
{
    const int i = blockIdx.x * blockDim.x + threadIdx.x;
    if (i < N_CAST) {
        const float4 v = ((const float4*)x)[i];
        const __half2 a = __floats2half2_rn(v.x, v.y);
        const __half2 b = __floats2half2_rn(v.z, v.w);
        uint2 u;
        u.x = *(const unsigned int*)&a;
        u.y = *(const unsigned int*)&b;
        ((uint2*)h16a)[i] = u;                       // single 8B store
    } else if (i < N_CAST + N_Z16) {
        ((uint4*)h16b)[i - N_CAST] = make_uint4(0u, 0u, 0u, 0u);
    } else {
        ((float4*)out)[i - (N_CAST + N_Z16)] = make_float4(0.f, 0.f, 0.f, 0.f);
    }
}

extern "C" void kernel_launch(void* const* d_in, const int* in_sizes, int n_in,
                              void* d_out, int out_size, void* d_ws, size_t ws_size,
                              hipStream_t stream) {
    const float* x    = (const float*)d_in[0];
    const int*   erow = (const int*)  d_in[1];
    const int*   ecol = (const int*)  d_in[2];
    const float* eval = (const float*)d_in[3];
    float*       out  = (float*)d_out;

    // ws layout: h16a [0, 12.8M) | h16b [12.8M, 25.6M)  (ws is 256 MiB)
    __half* h16a = (__half*)d_ws;
    __half* h16b = h16a + N_ELEM;

    const int threads     = 256;
    const int prep_blocks = PREP_TASKS / threads;             // 15625 exactly
    const int spmm_blocks = (N_EDGES / EPW) * 64 / threads;   // 6250 exactly

    prep<<<prep_blocks, threads, 0, stream>>>(x, h16a, h16b, out);
    sg_spmm<true ><<<spmm_blocks, threads, 0, stream>>>(h16a, erow, ecol, eval, h16b);
    sg_spmm<false><<<spmm_blocks, threads, 0, stream>>>(h16b, erow, ecol, eval, out);
}